// Round 6
// baseline (1693.687 us; speedup 1.0000x reference)
//
#include <hip/hip_runtime.h>
#include <cstdint>

// ---- problem constants ----
constexpr int B_       = 8;
constexpr int NPG_     = 12500;    // nodes per graph
constexpr int KSEL_    = 64;       // sort-pool k
constexpr int TOTAL_N_ = 100000;
constexpr int TOTAL_E_ = 1600000;
constexpr int NKEY_    = 16384;    // padded per-graph key count (pow2 >= NPG_)
constexpr int OUT_ROW  = KSEL_ * (128 + 32);       // 10240

// bucket geometry
constexpr int TILE_D   = 176;      // dst rows per tile (fits 8-bit local id)
constexpr int RPW_     = 22;       // rows per wave (8 waves * 22 = 176)
constexpr int NT_DST   = 72;       // ceil(12500/176) -> last tile 4 rows
constexpr int NT_SRC   = 8;        // src tiles: 1563 nodes = 400KB feat window
constexpr int SRC_TW   = 1563;
constexpr int NBKT     = B_ * NT_DST * 8 * NT_SRC;   // 36864 buckets
constexpr int NB_BSCAN = NBKT / 256;                 // 144

typedef float f2v __attribute__((ext_vector_type(2)));

__device__ __forceinline__ float lrelu(float v){ return v >= 0.f ? v : 0.01f * v; }
__device__ __forceinline__ int   rlanei(int x, int l){ return __builtin_amdgcn_readlane(x, l); }
__device__ __forceinline__ unsigned rlaneu(unsigned x, int l){ return (unsigned)__builtin_amdgcn_readlane((int)x, l); }
__device__ __forceinline__ float rlanef(float x, int l){
  return __uint_as_float(__builtin_amdgcn_readlane((int)__float_as_uint(x), l));
}

// ---------------- degrees ----------------
__global__ void deg_kernel(const int* __restrict__ src, const int* __restrict__ dst,
                           int* __restrict__ out_cnt, int* __restrict__ in_cnt){
  int i = blockIdx.x * 256 + threadIdx.x;
  if (i < TOTAL_E_){
    atomicAdd(&out_cnt[src[i]], 1);
    atomicAdd(&in_cnt[dst[i]], 1);
  }
}

__global__ void rsq_kernel(const int* __restrict__ in_cnt, const int* __restrict__ out_cnt,
                           float* __restrict__ rsq_in, float* __restrict__ rsq_out){
  int i = blockIdx.x * 256 + threadIdx.x;
  if (i < TOTAL_N_){
    int ic = in_cnt[i];  if (ic < 1) ic = 1;
    int oc = out_cnt[i]; if (oc < 1) oc = 1;
    rsq_in[i]  = rsqrtf((float)ic);
    rsq_out[i] = rsqrtf((float)oc);
  }
}

// ---------------- edge bucket key ----------------
__device__ __forceinline__ void edge_key(int s, int d, int& key, unsigned& pk){
  int g  = d / NPG_;             // src and dst share graph
  int dlc = d - g * NPG_;
  int slc = s - g * NPG_;
  int dt = dlc / TILE_D;
  int dl = dlc - dt * TILE_D;    // < 176
  int wsub = dl / RPW_;          // 0..7
  int st = slc / SRC_TW;         // 0..7
  key = (((g * NT_DST + dt) * 8 + wsub) * NT_SRC) + st;
  pk  = ((unsigned)slc << 8) | (unsigned)dl;
}

__global__ void bhist(const int* __restrict__ src, const int* __restrict__ dst,
                      int* __restrict__ bcnt){
  int i = blockIdx.x * 256 + threadIdx.x;
  if (i < TOTAL_E_){
    int key; unsigned pk;
    edge_key(src[i], dst[i], key, pk);
    atomicAdd(&bcnt[key], 1);
  }
}

// ---------------- generic exclusive scan (3 kernels) ----------------
__global__ void scan_blocks(const int* __restrict__ cnt, int* __restrict__ off,
                            int* __restrict__ bsum, int n){
  __shared__ int tmp[256];
  int t = threadIdx.x;
  int i = blockIdx.x * 256 + t;
  int x = (i < n) ? cnt[i] : 0;
  tmp[t] = x;
  __syncthreads();
  for (int d = 1; d < 256; d <<= 1){
    int v = (t >= d) ? tmp[t - d] : 0;
    __syncthreads();
    tmp[t] += v;
    __syncthreads();
  }
  if (i < n) off[i] = tmp[t] - x;
  if (t == 255) bsum[blockIdx.x] = tmp[255];
}

__global__ void scan_sums(int* __restrict__ bsum, int nb){
  __shared__ int tmp[512];
  int t = threadIdx.x;
  int x = (t < nb) ? bsum[t] : 0;
  tmp[t] = x;
  __syncthreads();
  for (int d = 1; d < 512; d <<= 1){
    int v = (t >= d) ? tmp[t - d] : 0;
    __syncthreads();
    tmp[t] += v;
    __syncthreads();
  }
  if (t < nb) bsum[t] = tmp[t] - x;
}

__global__ void scan_add(int* __restrict__ off, const int* __restrict__ bsum, int n){
  int i = blockIdx.x * 256 + threadIdx.x;
  if (i < n) off[i] += bsum[blockIdx.x];
}

// ---------------- bucket fill ----------------
// stored weight = ew * rsq_out[src] (serves BOTH layers; h2p omits rsq_out)
__global__ void bfill(const int* __restrict__ src, const int* __restrict__ dst,
                      const float* __restrict__ ew, const float* __restrict__ rsq_out,
                      const int* __restrict__ boff, int* __restrict__ bcur,
                      unsigned* __restrict__ bidx, float* __restrict__ bwr){
  int i = blockIdx.x * 256 + threadIdx.x;
  if (i < TOTAL_E_){
    int s = src[i], d = dst[i];
    int key; unsigned pk;
    edge_key(s, d, key, pk);
    int p = atomicAdd(&bcur[key], 1);
    int slot = boff[key] + p;
    bidx[slot] = pk;
    bwr[slot]  = ew[i] * rsq_out[s];
  }
}

// ---------------- layer 1: LDS-tile SpMM + W1 projection + stats ----------------
__global__ __launch_bounds__(512, 4)
void spmm1_tile(const int* __restrict__ boff, const unsigned* __restrict__ bidx,
                const float* __restrict__ bwr, const float* __restrict__ feat,
                const float* __restrict__ W1, const float* __restrict__ rsq_in,
                float* __restrict__ h1, float* __restrict__ gsum, float* __restrict__ gsq){
  __shared__ float agg[TILE_D * 64];   // 45056 B
  __shared__ float wsh[64 * 128];      // 32768 B  (total 77824 -> 2 blocks/CU)
  int t = threadIdx.x;
  int w = t >> 6, lane = t & 63;
  int g = blockIdx.x & 7, dt = blockIdx.x >> 3;    // 576 blocks: g in 0..7 (XCD), dt 0..71

  for (int i = t; i < TILE_D * 64; i += 512) agg[i] = 0.f;
  for (int i = t; i < 64 * 128;   i += 512) wsh[i] = W1[i];
  __syncthreads();

  // this wave's contiguous edge range: 8 src-tile buckets
  int kbase = (((g * NT_DST + dt) * 8) + w) * NT_SRC;
  int e0 = boff[kbase];
  int e1 = (kbase + NT_SRC < NBKT) ? boff[kbase + NT_SRC] : TOTAL_E_;

  const float* fg = feat + (size_t)g * NPG_ * 64;

  for (int e = e0; e < e1; e += 64){
    int m = e1 - e; if (m > 64) m = 64;
    unsigned pk = 0; float wr = 0.f;
    if (lane < m){ pk = bidx[e + lane]; wr = bwr[e + lane]; }
    int mr = (m + 3) & ~3;   // lanes >= m hold pk=0, wr=0 -> harmless zero adds
    for (int j = 0; j < mr; j += 4){
      unsigned p0 = rlaneu(pk, j+0), p1 = rlaneu(pk, j+1);
      unsigned p2 = rlaneu(pk, j+2), p3 = rlaneu(pk, j+3);
      float w0 = rlanef(wr, j+0), w1 = rlanef(wr, j+1);
      float w2 = rlanef(wr, j+2), w3 = rlanef(wr, j+3);
      float v0 = fg[(size_t)(p0 >> 8) * 64 + lane];
      float v1 = fg[(size_t)(p1 >> 8) * 64 + lane];
      float v2 = fg[(size_t)(p2 >> 8) * 64 + lane];
      float v3 = fg[(size_t)(p3 >> 8) * 64 + lane];
      atomicAdd(&agg[(p0 & 255) * 64 + lane], w0 * v0);
      atomicAdd(&agg[(p1 & 255) * 64 + lane], w1 * v1);
      atomicAdd(&agg[(p2 & 255) * 64 + lane], w2 * v2);
      atomicAdd(&agg[(p3 & 255) * 64 + lane], w3 * v3);
    }
  }
  __syncthreads();

  // projection: wave w projects rows [w*22, ...); lane owns cols 2*lane, 2*lane+1
  int rows = NPG_ - dt * TILE_D; if (rows > TILE_D) rows = TILE_D;
  float s0 = 0.f, q0 = 0.f, s1 = 0.f, q1 = 0.f;
  int rend = (w + 1) * RPW_; if (rend > rows) rend = rows;
  const f2v* wp = (const f2v*)wsh;
  for (int r = w * RPW_; r < rend; ++r){
    f2v A = {0.f, 0.f};
    #pragma unroll
    for (int k = 0; k < 64; ++k){
      float ak = agg[r * 64 + k];          // LDS broadcast read
      f2v wv = wp[k * 64 + lane];
      A.x = fmaf(ak, wv.x, A.x);
      A.y = fmaf(ak, wv.y, A.y);
    }
    int node = g * NPG_ + dt * TILE_D + r;
    float ri = rsq_in[node];
    A.x *= ri; A.y *= ri;
    *(f2v*)&h1[(size_t)node * 128 + 2 * lane] = A;
    s0 += A.x; q0 = fmaf(A.x, A.x, q0);
    s1 += A.y; q1 = fmaf(A.y, A.y, q1);
  }
  __syncthreads();
  // stats reduce in the (now dead) agg region
  float4* sred = (float4*)agg;
  sred[t] = make_float4(s0, q0, s1, q1);
  __syncthreads();
  if (t < 64){
    float S0 = 0.f, Q0 = 0.f, S1 = 0.f, Q1 = 0.f;
    #pragma unroll
    for (int ww = 0; ww < 8; ++ww){
      float4 v = sred[t + 64 * ww];
      S0 += v.x; Q0 += v.y; S1 += v.z; Q1 += v.w;
    }
    atomicAdd(&gsum[g * 128 + 2*t],     S0);
    atomicAdd(&gsq [g * 128 + 2*t],     Q0);
    atomicAdd(&gsum[g * 128 + 2*t + 1], S1);
    atomicAdd(&gsq [g * 128 + 2*t + 1], Q1);
  }
}

__global__ void finalize1(const float* __restrict__ gsum, const float* __restrict__ gsq,
                          const float* __restrict__ gamma, const float* __restrict__ beta,
                          const float* __restrict__ alpha, float* __restrict__ mul, float* __restrict__ add){
  int i = threadIdx.x;            // 1024 = 8*128
  int c = i & 127;
  const float invn = 1.0f / (float)NPG_;
  float m = gsum[i] * invn;
  float a = alpha[c];
  float var = gsq[i] * invn - 2.f * a * m * m + a * a * m * m;
  float mu = gamma[c] * rsqrtf(var + 1e-5f);
  mul[i] = mu;
  add[i] = beta[c] - mu * a * m;
}

// ---------------- fused: normalize h1 (in regs) + sort keys + project to h2p ----------------
// h2p = lrelu(norm(h1)) @ W2   (NO rsq_out factor; it lives in the bucket weights)
__global__ __launch_bounds__(256, 4)
void normproj(const float* __restrict__ h1,
              const float* __restrict__ mul, const float* __restrict__ add,
              const float* __restrict__ W2,
              unsigned long long* __restrict__ keys, float* __restrict__ h2p){
  __shared__ float w2s[128 * 32];  // 16 KB
  int t = threadIdx.x;
  for (int i = t; i < 128 * 32; i += 256) w2s[i] = W2[i];
  __syncthreads();

  int g     = blockIdx.x & 7;
  int wslot = (blockIdx.x >> 3) * 4 + (t >> 6);   // 0..511
  int lane  = t & 63;
  int c     = lane & 31, hh = lane >> 5;
  int wbase = hh * 64 * 32 + c;

  float m0 = mul[g * 128 + lane],      aa0 = add[g * 128 + lane];
  float m1 = mul[g * 128 + 64 + lane], aa1 = add[g * 128 + 64 + lane];

  int nv = (NPG_ - wslot + 511) / 512;

  int v0 = g * NPG_ + wslot;
  float x0 = h1[(size_t)v0 * 128 + lane];
  float x1 = h1[(size_t)v0 * 128 + 64 + lane];

  for (int i = 0; i < nv; ++i){
    int v = g * NPG_ + wslot + i * 512;
    float cur0 = x0, cur1 = x1;
    if (i + 1 < nv){
      int vn = v + 512;
      x0 = h1[(size_t)vn * 128 + lane];
      x1 = h1[(size_t)vn * 128 + 64 + lane];
    }
    float y0 = lrelu(fmaf(m0, cur0, aa0));
    float y1 = lrelu(fmaf(m1, cur1, aa1));
    float mx = fmaxf(y0, y1);
    for (int o = 1; o < 64; o <<= 1) mx = fmaxf(mx, __shfl_xor(mx, o));
    if (lane == 0){
      unsigned u = __float_as_uint(mx);
      u ^= (u >> 31) ? 0xFFFFFFFFu : 0x80000000u;
      int nloc = v - g * NPG_;
      keys[(size_t)g * NKEY_ + nloc] = ((unsigned long long)(~u) << 32) | (unsigned)nloc;
    }
    float acc = 0.f;
    #pragma unroll
    for (int kk = 0; kk < 64; ++kk){
      float sa = rlanef(y0, kk);
      float sb = rlanef(y1, kk);
      float vk = hh ? sb : sa;
      acc = fmaf(vk, w2s[wbase + kk * 32], acc);
    }
    acc += __shfl_xor(acc, 32);
    if (hh == 0) h2p[(size_t)v * 32 + c] = acc;
  }
}

// ---------------- top-k selection (2-stage bitonic) ----------------
__global__ void topk_s1(const unsigned long long* __restrict__ keys, unsigned long long* __restrict__ cand){
  __shared__ unsigned long long s[2048];
  int b = blockIdx.x >> 3, ch = blockIdx.x & 7;
  int t = threadIdx.x;            // 256
  for (int i = t; i < 2048; i += 256) s[i] = keys[(size_t)b * NKEY_ + (size_t)ch * 2048 + i];
  for (int k2 = 2; k2 <= 2048; k2 <<= 1){
    for (int j = k2 >> 1; j > 0; j >>= 1){
      __syncthreads();
      for (int i = t; i < 2048; i += 256){
        int p = i ^ j;
        if (p > i){
          unsigned long long A = s[i], C = s[p];
          bool up = ((i & k2) == 0);
          if ((A > C) == up){ s[i] = C; s[p] = A; }
        }
      }
    }
  }
  __syncthreads();
  if (t < 64) cand[(size_t)b * 512 + (size_t)ch * 64 + t] = s[t];
}

__global__ void topk_s2(const unsigned long long* __restrict__ cand, int* __restrict__ topidx){
  __shared__ unsigned long long s[512];
  int b = blockIdx.x;
  int t = threadIdx.x;            // 256
  for (int i = t; i < 512; i += 256) s[i] = cand[(size_t)b * 512 + i];
  for (int k2 = 2; k2 <= 512; k2 <<= 1){
    for (int j = k2 >> 1; j > 0; j >>= 1){
      __syncthreads();
      for (int i = t; i < 512; i += 256){
        int p = i ^ j;
        if (p > i){
          unsigned long long A = s[i], C = s[p];
          bool up = ((i & k2) == 0);
          if ((A > C) == up){ s[i] = C; s[p] = A; }
        }
      }
    }
  }
  __syncthreads();
  if (t < 64) topidx[b * 64 + t] = (int)(s[t] & 0xFFFFFFFFull);
}

// normalize selected raw h1 rows on the fly, sort 128 ascending, final leaky, write
__global__ void emit1(const float* __restrict__ h1, const int* __restrict__ topidx,
                      const float* __restrict__ mul, const float* __restrict__ add,
                      float* __restrict__ out){
  __shared__ float s[128];
  int b = blockIdx.x >> 6, k = blockIdx.x & 63;
  int t = threadIdx.x;            // 128
  int nloc = topidx[b * 64 + k];
  float raw = h1[((size_t)b * NPG_ + nloc) * 128 + t];
  s[t] = lrelu(fmaf(mul[b * 128 + t], raw, add[b * 128 + t]));
  for (int k2 = 2; k2 <= 128; k2 <<= 1){
    for (int j = k2 >> 1; j > 0; j >>= 1){
      __syncthreads();
      int p = t ^ j;
      if (p > t){
        float A = s[t], C = s[p];
        bool up = ((t & k2) == 0);
        if ((A > C) == up){ s[t] = C; s[p] = A; }
      }
    }
  }
  __syncthreads();
  out[(size_t)b * OUT_ROW + (size_t)k * 128 + t] = lrelu(s[t]);
}

// ---------------- layer 2: LDS-tile SpMM on h2p (32-d rows) + stats ----------------
__global__ __launch_bounds__(512, 4)
void spmm2_tile(const int* __restrict__ boff, const unsigned* __restrict__ bidx,
                const float* __restrict__ bwr, const float* __restrict__ h2p,
                const float* __restrict__ rsq_in, float* __restrict__ h2c,
                float* __restrict__ gsum, float* __restrict__ gsq){
  __shared__ float agg[TILE_D * 32];   // 22528 B
  int t = threadIdx.x;
  int w = t >> 6, lane = t & 63;
  int c = lane & 31, hh = lane >> 5;
  int g = blockIdx.x & 7, dt = blockIdx.x >> 3;

  for (int i = t; i < TILE_D * 32; i += 512) agg[i] = 0.f;
  __syncthreads();

  int kbase = (((g * NT_DST + dt) * 8) + w) * NT_SRC;
  int e0 = boff[kbase];
  int e1 = (kbase + NT_SRC < NBKT) ? boff[kbase + NT_SRC] : TOTAL_E_;

  const float* hg = h2p + (size_t)g * NPG_ * 32;

  for (int e = e0; e < e1; e += 64){
    int m = e1 - e; if (m > 64) m = 64;
    unsigned pk = 0; float wr = 0.f;
    if (lane < m){ pk = bidx[e + lane]; wr = bwr[e + lane]; }
    int mr = (m + 1) & ~1;
    for (int j = 0; j < mr; j += 2){
      unsigned pA = rlaneu(pk, j);     float wA = rlanef(wr, j);
      unsigned pB = rlaneu(pk, j + 1); float wB = rlanef(wr, j + 1);
      unsigned p = hh ? pB : pA;
      float   ww = hh ? wB : wA;
      float v = hg[(size_t)(p >> 8) * 32 + c];
      atomicAdd(&agg[(p & 255) * 32 + c], ww * v);   // half-waves may collide -> atomic
    }
  }
  __syncthreads();

  int rows = NPG_ - dt * TILE_D; if (rows > TILE_D) rows = TILE_D;
  float ssum = 0.f, ssq = 0.f;
  for (int idx = t; idx < rows * 32; idx += 512){
    int r = idx >> 5;
    int node = g * NPG_ + dt * TILE_D + r;
    float val = agg[idx] * rsq_in[node];
    h2c[(size_t)node * 32 + (idx & 31)] = val;
    ssum += val; ssq = fmaf(val, val, ssq);
  }
  __syncthreads();
  float2* sred = (float2*)agg;   // agg dead
  sred[t] = make_float2(ssum, ssq);
  __syncthreads();
  if (t < 32){
    float S = 0.f, Q = 0.f;
    #pragma unroll
    for (int k = 0; k < 16; ++k){
      float2 v = sred[t + 32 * k];
      S += v.x; Q += v.y;
    }
    atomicAdd(&gsum[g * 32 + t], S);
    atomicAdd(&gsq [g * 32 + t], Q);
  }
}

__global__ void finalize2(const float* __restrict__ gsum, const float* __restrict__ gsq,
                          const float* __restrict__ gamma, const float* __restrict__ beta,
                          const float* __restrict__ alpha, float* __restrict__ mul, float* __restrict__ add){
  int i = threadIdx.x;            // 256 = 8*32
  int c = i & 31;
  const float invn = 1.0f / (float)NPG_;
  float m = gsum[i] * invn;
  float a = alpha[c];
  float var = gsq[i] * invn - 2.f * a * m * m + a * a * m * m;
  float mu = gamma[c] * rsqrtf(var + 1e-5f);
  mul[i] = mu;
  add[i] = beta[c] - mu * a * m;
}

__global__ void norm2(float* __restrict__ h, const float* __restrict__ mul, const float* __restrict__ add,
                      unsigned long long* __restrict__ keys){
  int tid  = blockIdx.x * 256 + threadIdx.x;
  int node = tid >> 5;
  int sl   = tid & 31;
  if (node >= TOTAL_N_) return;
  int b = node / NPG_;
  int nloc = node - b * NPG_;
  float v = h[(size_t)node * 32 + sl];
  v = lrelu(fmaf(mul[b * 32 + sl], v, add[b * 32 + sl]));
  h[(size_t)node * 32 + sl] = v;
  float m = v;
  for (int o = 1; o < 32; o <<= 1) m = fmaxf(m, __shfl_xor(m, o));
  if (sl == 0){
    unsigned u = __float_as_uint(m);
    u ^= (u >> 31) ? 0xFFFFFFFFu : 0x80000000u;
    keys[(size_t)b * NKEY_ + nloc] = ((unsigned long long)(~u) << 32) | (unsigned)nloc;
  }
}

__global__ void emit2(const float* __restrict__ h2, const int* __restrict__ topidx, float* __restrict__ out){
  int b = blockIdx.x >> 6, k = blockIdx.x & 63;
  int lane = threadIdx.x;         // 32
  int nloc = topidx[b * 64 + k];
  float v = h2[((size_t)b * NPG_ + nloc) * 32 + lane];
  for (int k2 = 2; k2 <= 32; k2 <<= 1){
    for (int j = k2 >> 1; j > 0; j >>= 1){
      float o = __shfl_xor(v, j);
      bool up    = ((lane & k2) == 0);
      bool lower = ((lane & j) == 0);
      v = (up == lower) ? fminf(v, o) : fmaxf(v, o);
    }
  }
  out[(size_t)b * OUT_ROW + 8192 + (size_t)k * 32 + lane] = lrelu(v);
}

__global__ void sentinel_kernel(float* out){
  int i = blockIdx.x * 256 + threadIdx.x;
  if (i < B_ * OUT_ROW) out[i] = -777.0f;
}

extern "C" void kernel_launch(void* const* d_in, const int* in_sizes, int n_in,
                              void* d_out, int out_size, void* d_ws, size_t ws_size,
                              hipStream_t stream){
  const float* feat   = (const float*)d_in[0];
  const float* ew     = (const float*)d_in[1];
  const float* W1     = (const float*)d_in[2];
  const float* W2     = (const float*)d_in[3];
  const float* gamma1 = (const float*)d_in[4];
  const float* beta1  = (const float*)d_in[5];
  const float* alpha1 = (const float*)d_in[6];
  const float* gamma2 = (const float*)d_in[7];
  const float* beta2  = (const float*)d_in[8];
  const float* alpha2 = (const float*)d_in[9];
  const int*   esrc   = (const int*)d_in[10];
  const int*   edst   = (const int*)d_in[11];
  float* out = (float*)d_out;

  char* ws = (char*)d_ws;
  auto alloc = [&](size_t bytes) -> char* {
    char* p = ws;
    ws += (bytes + 255) & ~(size_t)255;
    return p;
  };

  // zeroed region (must stay first & contiguous)
  int*   in_cnt  = (int*)  alloc((size_t)TOTAL_N_ * 4);
  int*   out_cnt = (int*)  alloc((size_t)TOTAL_N_ * 4);
  int*   bcnt    = (int*)  alloc((size_t)NBKT * 4);
  int*   bcur    = (int*)  alloc((size_t)NBKT * 4);
  float* gsum1   = (float*)alloc(1024 * 4);
  float* gsq1    = (float*)alloc(1024 * 4);
  float* gsum2   = (float*)alloc(256 * 4);
  float* gsq2    = (float*)alloc(256 * 4);
  size_t zero_bytes = (size_t)(ws - (char*)d_ws);

  float* rsq_in  = (float*)alloc((size_t)TOTAL_N_ * 4);
  float* rsq_out = (float*)alloc((size_t)TOTAL_N_ * 4);
  int*   boff    = (int*)  alloc((size_t)NBKT * 4);
  int*   bsum    = (int*)  alloc(512 * 4);
  float* mul1    = (float*)alloc(1024 * 4);
  float* add1    = (float*)alloc(1024 * 4);
  float* mul2    = (float*)alloc(256 * 4);
  float* add2    = (float*)alloc(256 * 4);
  int*   topidx1 = (int*)  alloc(512 * 4);
  int*   topidx2 = (int*)  alloc(512 * 4);
  unsigned long long* cand = (unsigned long long*)alloc((size_t)B_ * 512 * 8);
  unsigned long long* keys = (unsigned long long*)alloc((size_t)B_ * NKEY_ * 8);
  unsigned* bidx = (unsigned*)alloc((size_t)TOTAL_E_ * 4);
  float*    bwr  = (float*)   alloc((size_t)TOTAL_E_ * 4);
  float* h2p     = (float*)alloc((size_t)TOTAL_N_ * 32 * 4);
  float* h2c     = (float*)alloc((size_t)TOTAL_N_ * 32 * 4);
  float* h1      = (float*)alloc((size_t)TOTAL_N_ * 128 * 4);

  size_t need = (size_t)(ws - (char*)d_ws);
  if (need > ws_size){
    sentinel_kernel<<<(B_ * OUT_ROW + 255) / 256, 256, 0, stream>>>(out);
    return;
  }

  hipMemsetAsync(d_ws, 0, zero_bytes, stream);
  hipMemsetAsync(keys, 0xFF, (size_t)B_ * NKEY_ * 8, stream);

  const int EB = (TOTAL_E_ + 255) / 256;           // 6250
  deg_kernel <<<EB, 256, 0, stream>>>(esrc, edst, out_cnt, in_cnt);
  rsq_kernel <<<(TOTAL_N_ + 255) / 256, 256, 0, stream>>>(in_cnt, out_cnt, rsq_in, rsq_out);
  bhist      <<<EB, 256, 0, stream>>>(esrc, edst, bcnt);
  scan_blocks<<<NB_BSCAN, 256, 0, stream>>>(bcnt, boff, bsum, NBKT);
  scan_sums  <<<1, 512, 0, stream>>>(bsum, NB_BSCAN);
  scan_add   <<<NB_BSCAN, 256, 0, stream>>>(boff, bsum, NBKT);
  bfill      <<<EB, 256, 0, stream>>>(esrc, edst, ew, rsq_out, boff, bcur, bidx, bwr);

  // layer 1
  spmm1_tile <<<NT_DST * 8, 512, 0, stream>>>(boff, bidx, bwr, feat, W1, rsq_in, h1, gsum1, gsq1);
  finalize1  <<<1, 1024, 0, stream>>>(gsum1, gsq1, gamma1, beta1, alpha1, mul1, add1);
  normproj   <<<1024, 256, 0, stream>>>(h1, mul1, add1, W2, keys, h2p);
  topk_s1    <<<B_ * 8, 256, 0, stream>>>(keys, cand);
  topk_s2    <<<B_, 256, 0, stream>>>(cand, topidx1);
  emit1      <<<B_ * 64, 128, 0, stream>>>(h1, topidx1, mul1, add1, out);

  // layer 2
  spmm2_tile <<<NT_DST * 8, 512, 0, stream>>>(boff, bidx, bwr, h2p, rsq_in, h2c, gsum2, gsq2);
  finalize2  <<<1, 256, 0, stream>>>(gsum2, gsq2, gamma2, beta2, alpha2, mul2, add2);
  norm2      <<<TOTAL_N_ * 32 / 256, 256, 0, stream>>>(h2c, mul2, add2, keys);
  topk_s1    <<<B_ * 8, 256, 0, stream>>>(keys, cand);
  topk_s2    <<<B_, 256, 0, stream>>>(cand, topidx2);
  emit2      <<<B_ * 64, 32, 0, stream>>>(h2c, topidx2, out);
}

// Round 7
// 771.210 us; speedup vs baseline: 2.1961x; 2.1961x over previous
//
#include <hip/hip_runtime.h>
#include <cstdint>

// ---- problem constants ----
constexpr int B_       = 8;
constexpr int NPG_     = 12500;    // nodes per graph
constexpr int KSEL_    = 64;       // sort-pool k
constexpr int TOTAL_N_ = 100000;
constexpr int TOTAL_E_ = 1600000;
constexpr int NKEY_    = 16384;    // padded per-graph key count (pow2 >= NPG_)
constexpr int NB_SCAN  = (TOTAL_N_ + 255) / 256;   // 391
constexpr int OUT_ROW  = KSEL_ * (128 + 32);       // 10240
constexpr int NBLK_    = 1024;     // 256-thread blocks, 4 blocks/CU
constexpr int WSTRIDE_ = 512;      // wave slots per graph (1024 blocks * 4 waves / 8 graphs)

typedef float f2v __attribute__((ext_vector_type(2)));

__device__ __forceinline__ float lrelu(float v){ return v >= 0.f ? v : 0.01f * v; }
__device__ __forceinline__ int   rlanei(int x, int l){ return __builtin_amdgcn_readlane(x, l); }
__device__ __forceinline__ float rlanef(float x, int l){
  return __uint_as_float(__builtin_amdgcn_readlane((int)__float_as_uint(x), l));
}

// ---------------- degrees ----------------
__global__ void deg_kernel(const int* __restrict__ src, const int* __restrict__ dst,
                           int* __restrict__ out_cnt, int* __restrict__ in_cnt){
  int i = blockIdx.x * 256 + threadIdx.x;
  if (i < TOTAL_E_){
    atomicAdd(&out_cnt[src[i]], 1);
    atomicAdd(&in_cnt[dst[i]], 1);
  }
}

__global__ void rsq_kernel(const int* __restrict__ in_cnt, const int* __restrict__ out_cnt,
                           float* __restrict__ rsq_in, float* __restrict__ rsq_out){
  int i = blockIdx.x * 256 + threadIdx.x;
  if (i < TOTAL_N_){
    int ic = in_cnt[i];  if (ic < 1) ic = 1;
    int oc = out_cnt[i]; if (oc < 1) oc = 1;
    rsq_in[i]  = rsqrtf((float)ic);
    rsq_out[i] = rsqrtf((float)oc);
  }
}

// ---------------- exclusive scan (3 kernels) ----------------
__global__ void scan_blocks(const int* __restrict__ cnt, int* __restrict__ off, int* __restrict__ bsum){
  __shared__ int tmp[256];
  int t = threadIdx.x;
  int i = blockIdx.x * 256 + t;
  int x = (i < TOTAL_N_) ? cnt[i] : 0;
  tmp[t] = x;
  __syncthreads();
  for (int d = 1; d < 256; d <<= 1){
    int v = (t >= d) ? tmp[t - d] : 0;
    __syncthreads();
    tmp[t] += v;
    __syncthreads();
  }
  if (i < TOTAL_N_) off[i] = tmp[t] - x;
  if (t == 255) bsum[blockIdx.x] = tmp[255];
}

__global__ void scan_sums(int* __restrict__ bsum, int nb){
  __shared__ int tmp[512];
  int t = threadIdx.x;
  int x = (t < nb) ? bsum[t] : 0;
  tmp[t] = x;
  __syncthreads();
  for (int d = 1; d < 512; d <<= 1){
    int v = (t >= d) ? tmp[t - d] : 0;
    __syncthreads();
    tmp[t] += v;
    __syncthreads();
  }
  if (t < nb) bsum[t] = tmp[t] - x;
}

__global__ void scan_add(int* __restrict__ off, const int* __restrict__ bsum){
  int i = blockIdx.x * 256 + threadIdx.x;
  if (i < TOTAL_N_) off[i] += bsum[blockIdx.x];
}

// ---------------- CSR fill (bucket by dst) ----------------
__global__ void fill_csr(const int* __restrict__ src, const int* __restrict__ dst,
                         const float* __restrict__ ew, const float* __restrict__ rsq_out,
                         const int* __restrict__ off, int* __restrict__ cursor,
                         int* __restrict__ csr_src, float* __restrict__ csr_w,
                         float* __restrict__ csr_wr){
  int i = blockIdx.x * 256 + threadIdx.x;
  if (i < TOTAL_E_){
    int s = src[i];
    int d = dst[i];
    float w = ew[i];
    int p = atomicAdd(&cursor[d], 1);
    int slot = off[d] + p;
    csr_src[slot] = s;
    csr_w[slot]   = w;
    csr_wr[slot]  = w * rsq_out[s];
  }
}

// ---------------- layer 1: fused SpMM (64-d, paired float2 gather) + W1 proj + stats ----------------
// h1_raw[v][c] = rsq_in[v] * sum_k ( sum_e csr_wr * feat[src][k] ) * W1[k][c]
__global__ __launch_bounds__(256, 4)
void spmm1_fused(const int* __restrict__ off, const int* __restrict__ cnt,
                 const int* __restrict__ csr_src, const float* __restrict__ csr_wr,
                 const float* __restrict__ feat, const float* __restrict__ W1,
                 const float* __restrict__ rsq_in, float* __restrict__ h1,
                 float* __restrict__ gsum, float* __restrict__ gsq){
  __shared__ float wsh[64 * 128];   // 32 KB
  __shared__ float sred[4][256];    // 4 KB
  int t = threadIdx.x;
  for (int i = t; i < 64 * 128; i += 256) wsh[i] = W1[i];
  __syncthreads();

  int g     = blockIdx.x & 7;                       // graph == XCD round-robin
  int wslot = (blockIdx.x >> 3) * 4 + (t >> 6);     // 0..511
  int lane  = t & 63;
  int c2    = lane & 31, half = lane >> 5;          // paired-gather mapping

  // lane i (<32) holds off/cnt of node (wslot + i*WSTRIDE_)
  int pof = 0, pcn = 0;
  {
    int nl = wslot + lane * WSTRIDE_;
    if (lane < 32 && nl < NPG_){
      int v = g * NPG_ + nl;
      pof = off[v];
      pcn = cnt[v];
    }
  }
  int nv = (NPG_ - wslot + WSTRIDE_ - 1) / WSTRIDE_;   // 24 or 25

  const f2v* fg2 = (const f2v*)feat;
  float s0 = 0.f, q0 = 0.f, s1 = 0.f, q1 = 0.f;

  // csr batch prefetch pipeline
  int ms = 0, msn = 0; float mw = 0.f, mwn = 0.f;
  {
    int sb = rlanei(pof, 0);
    int n  = rlanei(pcn, 0);
    int b  = n < 64 ? n : 64;
    if (lane < b){ ms = csr_src[sb + lane]; mw = csr_wr[sb + lane]; }
  }

  for (int i = 0; i < nv; ++i){
    int sbase = rlanei(pof, i);
    int n     = rlanei(pcn, i);
    int batch = n < 64 ? n : 64;
    if (i + 1 < nv){
      int sb = rlanei(pof, i + 1);
      int n1 = rlanei(pcn, i + 1);
      int b1 = n1 < 64 ? n1 : 64;
      msn = 0; mwn = 0.f;
      if (lane < b1){ msn = csr_src[sb + lane]; mwn = csr_wr[sb + lane]; }
    }

    // paired gather: lower half-wave takes even edges, upper half odd edges.
    // each lane loads float2 (cols 2*c2, 2*c2+1). lanes >= batch hold ms=0,mw=0.
    f2v acc = {0.f, 0.f};
    int mr = (batch + 15) & ~15;
    #pragma unroll 1
    for (int j = 0; j < mr; j += 16){
      int   sL0 = rlanei(ms, j+ 0), sH0 = rlanei(ms, j+ 1);
      int   sL1 = rlanei(ms, j+ 2), sH1 = rlanei(ms, j+ 3);
      int   sL2 = rlanei(ms, j+ 4), sH2 = rlanei(ms, j+ 5);
      int   sL3 = rlanei(ms, j+ 6), sH3 = rlanei(ms, j+ 7);
      int   sL4 = rlanei(ms, j+ 8), sH4 = rlanei(ms, j+ 9);
      int   sL5 = rlanei(ms, j+10), sH5 = rlanei(ms, j+11);
      int   sL6 = rlanei(ms, j+12), sH6 = rlanei(ms, j+13);
      int   sL7 = rlanei(ms, j+14), sH7 = rlanei(ms, j+15);
      float wL0 = rlanef(mw, j+ 0), wH0 = rlanef(mw, j+ 1);
      float wL1 = rlanef(mw, j+ 2), wH1 = rlanef(mw, j+ 3);
      float wL2 = rlanef(mw, j+ 4), wH2 = rlanef(mw, j+ 5);
      float wL3 = rlanef(mw, j+ 6), wH3 = rlanef(mw, j+ 7);
      float wL4 = rlanef(mw, j+ 8), wH4 = rlanef(mw, j+ 9);
      float wL5 = rlanef(mw, j+10), wH5 = rlanef(mw, j+11);
      float wL6 = rlanef(mw, j+12), wH6 = rlanef(mw, j+13);
      float wL7 = rlanef(mw, j+14), wH7 = rlanef(mw, j+15);
      int   e0 = half ? sH0 : sL0;  float g0 = half ? wH0 : wL0;
      int   e1 = half ? sH1 : sL1;  float g1 = half ? wH1 : wL1;
      int   e2 = half ? sH2 : sL2;  float g2 = half ? wH2 : wL2;
      int   e3 = half ? sH3 : sL3;  float g3 = half ? wH3 : wL3;
      int   e4 = half ? sH4 : sL4;  float g4 = half ? wH4 : wL4;
      int   e5 = half ? sH5 : sL5;  float g5 = half ? wH5 : wL5;
      int   e6 = half ? sH6 : sL6;  float g6 = half ? wH6 : wL6;
      int   e7 = half ? sH7 : sL7;  float g7 = half ? wH7 : wL7;
      f2v v0 = fg2[(size_t)e0 * 32 + c2];
      f2v v1 = fg2[(size_t)e1 * 32 + c2];
      f2v v2 = fg2[(size_t)e2 * 32 + c2];
      f2v v3 = fg2[(size_t)e3 * 32 + c2];
      f2v v4 = fg2[(size_t)e4 * 32 + c2];
      f2v v5 = fg2[(size_t)e5 * 32 + c2];
      f2v v6 = fg2[(size_t)e6 * 32 + c2];
      f2v v7 = fg2[(size_t)e7 * 32 + c2];
      acc.x = fmaf(g0, v0.x, acc.x); acc.y = fmaf(g0, v0.y, acc.y);
      acc.x = fmaf(g1, v1.x, acc.x); acc.y = fmaf(g1, v1.y, acc.y);
      acc.x = fmaf(g2, v2.x, acc.x); acc.y = fmaf(g2, v2.y, acc.y);
      acc.x = fmaf(g3, v3.x, acc.x); acc.y = fmaf(g3, v3.y, acc.y);
      acc.x = fmaf(g4, v4.x, acc.x); acc.y = fmaf(g4, v4.y, acc.y);
      acc.x = fmaf(g5, v5.x, acc.x); acc.y = fmaf(g5, v5.y, acc.y);
      acc.x = fmaf(g6, v6.x, acc.x); acc.y = fmaf(g6, v6.y, acc.y);
      acc.x = fmaf(g7, v7.x, acc.x); acc.y = fmaf(g7, v7.y, acc.y);
    }
    // combine halves: every lane gets totals for cols 2*c2, 2*c2+1
    acc.x += __shfl_xor(acc.x, 32);
    acc.y += __shfl_xor(acc.y, 32);
    if (n > 64){   // statistically never; correctness fallback (post-combine: add once)
      for (int e = 64; e < n; ++e){
        int s = csr_src[sbase + e];
        float wv = csr_wr[sbase + e];
        f2v v = fg2[(size_t)s * 32 + c2];
        acc.x = fmaf(wv, v.x, acc.x);
        acc.y = fmaf(wv, v.y, acc.y);
      }
    }

    // epilogue: project 64 -> 128; lane owns output cols 2*lane, 2*lane+1
    f2v A = {0.f, 0.f};
    const f2v* wp = (const f2v*)wsh;
    #pragma unroll
    for (int k = 0; k < 64; ++k){
      float ak = (k & 1) ? rlanef(acc.y, k >> 1) : rlanef(acc.x, k >> 1);
      f2v wv = wp[k * 64 + lane];
      A.x = fmaf(ak, wv.x, A.x);
      A.y = fmaf(ak, wv.y, A.y);
    }
    int v = g * NPG_ + wslot + i * WSTRIDE_;
    float ri = rsq_in[v];
    A.x *= ri; A.y *= ri;
    *(f2v*)&h1[(size_t)v * 128 + 2 * lane] = A;
    s0 += A.x; q0 = fmaf(A.x, A.x, q0);
    s1 += A.y; q1 = fmaf(A.y, A.y, q1);

    ms = msn; mw = mwn;
  }

  // block-level stats reduce (all 4 waves same graph), then atomics
  __syncthreads();
  sred[0][t] = s0; sred[1][t] = q0; sred[2][t] = s1; sred[3][t] = q1;
  __syncthreads();
  if (t < 64){
    float S0 = sred[0][t] + sred[0][t+64] + sred[0][t+128] + sred[0][t+192];
    float Q0 = sred[1][t] + sred[1][t+64] + sred[1][t+128] + sred[1][t+192];
    float S1 = sred[2][t] + sred[2][t+64] + sred[2][t+128] + sred[2][t+192];
    float Q1 = sred[3][t] + sred[3][t+64] + sred[3][t+128] + sred[3][t+192];
    atomicAdd(&gsum[g * 128 + 2*t],     S0);
    atomicAdd(&gsq [g * 128 + 2*t],     Q0);
    atomicAdd(&gsum[g * 128 + 2*t + 1], S1);
    atomicAdd(&gsq [g * 128 + 2*t + 1], Q1);
  }
}

__global__ void finalize1(const float* __restrict__ gsum, const float* __restrict__ gsq,
                          const float* __restrict__ gamma, const float* __restrict__ beta,
                          const float* __restrict__ alpha, float* __restrict__ mul, float* __restrict__ add){
  int i = threadIdx.x;            // 1024 = 8*128
  int c = i & 127;
  const float invn = 1.0f / (float)NPG_;
  float m = gsum[i] * invn;
  float a = alpha[c];
  float var = gsq[i] * invn - 2.f * a * m * m + a * a * m * m;
  float mu = gamma[c] * rsqrtf(var + 1e-5f);
  mul[i] = mu;
  add[i] = beta[c] - mu * a * m;
}

// ---------------- fused: normalize h1 (in regs) + sort keys + project to h2p ----------------
__global__ __launch_bounds__(256, 4)
void normproj(const float* __restrict__ h1,
              const float* __restrict__ mul, const float* __restrict__ add,
              const float* __restrict__ rsq_out, const float* __restrict__ W2,
              unsigned long long* __restrict__ keys, float* __restrict__ h2p){
  __shared__ float w2s[128 * 32];  // 16 KB
  int t = threadIdx.x;
  for (int i = t; i < 128 * 32; i += 256) w2s[i] = W2[i];
  __syncthreads();

  int g     = blockIdx.x & 7;
  int wslot = (blockIdx.x >> 3) * 4 + (t >> 6);
  int lane  = t & 63;
  int c     = lane & 31, hh = lane >> 5;
  int wbase = hh * 64 * 32 + c;

  float m0 = mul[g * 128 + lane],      aa0 = add[g * 128 + lane];
  float m1 = mul[g * 128 + 64 + lane], aa1 = add[g * 128 + 64 + lane];

  int nv = (NPG_ - wslot + WSTRIDE_ - 1) / WSTRIDE_;

  int v0 = g * NPG_ + wslot;
  float x0 = h1[(size_t)v0 * 128 + lane];
  float x1 = h1[(size_t)v0 * 128 + 64 + lane];

  for (int i = 0; i < nv; ++i){
    int v = g * NPG_ + wslot + i * WSTRIDE_;
    float cur0 = x0, cur1 = x1;
    if (i + 1 < nv){
      int vn = v + WSTRIDE_;
      x0 = h1[(size_t)vn * 128 + lane];
      x1 = h1[(size_t)vn * 128 + 64 + lane];
    }
    float y0 = lrelu(fmaf(m0, cur0, aa0));
    float y1 = lrelu(fmaf(m1, cur1, aa1));
    float mx = fmaxf(y0, y1);
    for (int o = 1; o < 64; o <<= 1) mx = fmaxf(mx, __shfl_xor(mx, o));
    if (lane == 0){
      unsigned u = __float_as_uint(mx);
      u ^= (u >> 31) ? 0xFFFFFFFFu : 0x80000000u;
      int nloc = v - g * NPG_;
      keys[(size_t)g * NKEY_ + nloc] = ((unsigned long long)(~u) << 32) | (unsigned)nloc;
    }
    float acc = 0.f;
    #pragma unroll
    for (int kk = 0; kk < 64; ++kk){
      float sa = rlanef(y0, kk);
      float sb = rlanef(y1, kk);
      float vk = hh ? sb : sa;
      acc = fmaf(vk, w2s[wbase + kk * 32], acc);
    }
    acc += __shfl_xor(acc, 32);
    if (hh == 0) h2p[(size_t)v * 32 + c] = acc * rsq_out[v];
  }
}

// ---------------- top-k selection (2-stage bitonic) ----------------
__global__ void topk_s1(const unsigned long long* __restrict__ keys, unsigned long long* __restrict__ cand){
  __shared__ unsigned long long s[2048];
  int b = blockIdx.x >> 3, ch = blockIdx.x & 7;
  int t = threadIdx.x;            // 256
  for (int i = t; i < 2048; i += 256) s[i] = keys[(size_t)b * NKEY_ + (size_t)ch * 2048 + i];
  for (int k2 = 2; k2 <= 2048; k2 <<= 1){
    for (int j = k2 >> 1; j > 0; j >>= 1){
      __syncthreads();
      for (int i = t; i < 2048; i += 256){
        int p = i ^ j;
        if (p > i){
          unsigned long long A = s[i], C = s[p];
          bool up = ((i & k2) == 0);
          if ((A > C) == up){ s[i] = C; s[p] = A; }
        }
      }
    }
  }
  __syncthreads();
  if (t < 64) cand[(size_t)b * 512 + (size_t)ch * 64 + t] = s[t];
}

__global__ void topk_s2(const unsigned long long* __restrict__ cand, int* __restrict__ topidx){
  __shared__ unsigned long long s[512];
  int b = blockIdx.x;
  int t = threadIdx.x;            // 256
  for (int i = t; i < 512; i += 256) s[i] = cand[(size_t)b * 512 + i];
  for (int k2 = 2; k2 <= 512; k2 <<= 1){
    for (int j = k2 >> 1; j > 0; j >>= 1){
      __syncthreads();
      for (int i = t; i < 512; i += 256){
        int p = i ^ j;
        if (p > i){
          unsigned long long A = s[i], C = s[p];
          bool up = ((i & k2) == 0);
          if ((A > C) == up){ s[i] = C; s[p] = A; }
        }
      }
    }
  }
  __syncthreads();
  if (t < 64) topidx[b * 64 + t] = (int)(s[t] & 0xFFFFFFFFull);
}

// normalize selected raw h1 rows on the fly, sort 128 ascending, final leaky, write
__global__ void emit1(const float* __restrict__ h1, const int* __restrict__ topidx,
                      const float* __restrict__ mul, const float* __restrict__ add,
                      float* __restrict__ out){
  __shared__ float s[128];
  int b = blockIdx.x >> 6, k = blockIdx.x & 63;
  int t = threadIdx.x;            // 128
  int nloc = topidx[b * 64 + k];
  float raw = h1[((size_t)b * NPG_ + nloc) * 128 + t];
  s[t] = lrelu(fmaf(mul[b * 128 + t], raw, add[b * 128 + t]));
  for (int k2 = 2; k2 <= 128; k2 <<= 1){
    for (int j = k2 >> 1; j > 0; j >>= 1){
      __syncthreads();
      int p = t ^ j;
      if (p > t){
        float A = s[t], C = s[p];
        bool up = ((t & k2) == 0);
        if ((A > C) == up){ s[t] = C; s[p] = A; }
      }
    }
  }
  __syncthreads();
  out[(size_t)b * OUT_ROW + (size_t)k * 128 + t] = lrelu(s[t]);
}

// ---------------- layer 2: SpMM on projected h2p (32-d rows) + stats ----------------
__global__ __launch_bounds__(256, 4)
void spmm2_fused(const int* __restrict__ off, const int* __restrict__ cnt,
                 const int* __restrict__ csr_src, const float* __restrict__ csr_w,
                 const float* __restrict__ rsq_in, const float* __restrict__ h2p,
                 float* __restrict__ h2c,
                 float* __restrict__ gsum, float* __restrict__ gsq){
  __shared__ float sred[2][256];
  int t     = threadIdx.x;
  int g     = blockIdx.x & 7;
  int wslot = (blockIdx.x >> 3) * 4 + (t >> 6);
  int lane  = t & 63;
  int c     = lane & 31, hh = lane >> 5;

  int pof = 0, pcn = 0;
  {
    int nl = wslot + lane * WSTRIDE_;
    if (lane < 32 && nl < NPG_){
      int v = g * NPG_ + nl;
      pof = off[v];
      pcn = cnt[v];
    }
  }
  int nv = (NPG_ - wslot + WSTRIDE_ - 1) / WSTRIDE_;

  float ssum = 0.f, ssq = 0.f;

  int ms = 0, msn = 0; float mw = 0.f, mwn = 0.f;
  {
    int sb = rlanei(pof, 0);
    int n  = rlanei(pcn, 0);
    int b  = n < 64 ? n : 64;
    if (lane < b){ ms = csr_src[sb + lane]; mw = csr_w[sb + lane]; }
  }

  for (int i = 0; i < nv; ++i){
    int sbase = rlanei(pof, i);
    int n     = rlanei(pcn, i);
    int batch = n < 64 ? n : 64;
    if (i + 1 < nv){
      int sb = rlanei(pof, i + 1);
      int n1 = rlanei(pcn, i + 1);
      int b1 = n1 < 64 ? n1 : 64;
      msn = 0; mwn = 0.f;
      if (lane < b1){ msn = csr_src[sb + lane]; mwn = csr_w[sb + lane]; }
    }

    // paired: lower half even edges, upper half odd edges; 8 loads in flight.
    float acc = 0.f;
    int mr = (batch + 15) & ~15;
    #pragma unroll 1
    for (int j = 0; j < mr; j += 16){
      int   sL0 = rlanei(ms, j+ 0), sH0 = rlanei(ms, j+ 1);
      int   sL1 = rlanei(ms, j+ 2), sH1 = rlanei(ms, j+ 3);
      int   sL2 = rlanei(ms, j+ 4), sH2 = rlanei(ms, j+ 5);
      int   sL3 = rlanei(ms, j+ 6), sH3 = rlanei(ms, j+ 7);
      int   sL4 = rlanei(ms, j+ 8), sH4 = rlanei(ms, j+ 9);
      int   sL5 = rlanei(ms, j+10), sH5 = rlanei(ms, j+11);
      int   sL6 = rlanei(ms, j+12), sH6 = rlanei(ms, j+13);
      int   sL7 = rlanei(ms, j+14), sH7 = rlanei(ms, j+15);
      float wL0 = rlanef(mw, j+ 0), wH0 = rlanef(mw, j+ 1);
      float wL1 = rlanef(mw, j+ 2), wH1 = rlanef(mw, j+ 3);
      float wL2 = rlanef(mw, j+ 4), wH2 = rlanef(mw, j+ 5);
      float wL3 = rlanef(mw, j+ 6), wH3 = rlanef(mw, j+ 7);
      float wL4 = rlanef(mw, j+ 8), wH4 = rlanef(mw, j+ 9);
      float wL5 = rlanef(mw, j+10), wH5 = rlanef(mw, j+11);
      float wL6 = rlanef(mw, j+12), wH6 = rlanef(mw, j+13);
      float wL7 = rlanef(mw, j+14), wH7 = rlanef(mw, j+15);
      int   e0 = hh ? sH0 : sL0;  float g0 = hh ? wH0 : wL0;
      int   e1 = hh ? sH1 : sL1;  float g1 = hh ? wH1 : wL1;
      int   e2 = hh ? sH2 : sL2;  float g2 = hh ? wH2 : wL2;
      int   e3 = hh ? sH3 : sL3;  float g3 = hh ? wH3 : wL3;
      int   e4 = hh ? sH4 : sL4;  float g4 = hh ? wH4 : wL4;
      int   e5 = hh ? sH5 : sL5;  float g5 = hh ? wH5 : wL5;
      int   e6 = hh ? sH6 : sL6;  float g6 = hh ? wH6 : wL6;
      int   e7 = hh ? sH7 : sL7;  float g7 = hh ? wH7 : wL7;
      float f0 = h2p[(size_t)e0 * 32 + c];
      float f1 = h2p[(size_t)e1 * 32 + c];
      float f2 = h2p[(size_t)e2 * 32 + c];
      float f3 = h2p[(size_t)e3 * 32 + c];
      float f4 = h2p[(size_t)e4 * 32 + c];
      float f5 = h2p[(size_t)e5 * 32 + c];
      float f6 = h2p[(size_t)e6 * 32 + c];
      float f7 = h2p[(size_t)e7 * 32 + c];
      acc = fmaf(g0, f0, acc); acc = fmaf(g1, f1, acc);
      acc = fmaf(g2, f2, acc); acc = fmaf(g3, f3, acc);
      acc = fmaf(g4, f4, acc); acc = fmaf(g5, f5, acc);
      acc = fmaf(g6, f6, acc); acc = fmaf(g7, f7, acc);
    }
    acc += __shfl_xor(acc, 32);
    if (n > 64){
      for (int e = 64; e < n; ++e)
        acc = fmaf(csr_w[sbase + e], h2p[(size_t)csr_src[sbase + e] * 32 + c], acc);
    }
    int v = g * NPG_ + wslot + i * WSTRIDE_;
    float val = acc * rsq_in[v];
    if (hh == 0){
      h2c[(size_t)v * 32 + c] = val;
      ssum += val; ssq = fmaf(val, val, ssq);
    }
    ms = msn; mw = mwn;
  }

  __syncthreads();
  sred[0][t] = ssum; sred[1][t] = ssq;
  __syncthreads();
  if (t < 32){
    float S = 0.f, Q = 0.f;
    #pragma unroll
    for (int w = 0; w < 4; ++w){
      S += sred[0][t + 64*w] + sred[0][t + 32 + 64*w];
      Q += sred[1][t + 64*w] + sred[1][t + 32 + 64*w];
    }
    atomicAdd(&gsum[g * 32 + t], S);
    atomicAdd(&gsq [g * 32 + t], Q);
  }
}

__global__ void finalize2(const float* __restrict__ gsum, const float* __restrict__ gsq,
                          const float* __restrict__ gamma, const float* __restrict__ beta,
                          const float* __restrict__ alpha, float* __restrict__ mul, float* __restrict__ add){
  int i = threadIdx.x;            // 256 = 8*32
  int c = i & 31;
  const float invn = 1.0f / (float)NPG_;
  float m = gsum[i] * invn;
  float a = alpha[c];
  float var = gsq[i] * invn - 2.f * a * m * m + a * a * m * m;
  float mu = gamma[c] * rsqrtf(var + 1e-5f);
  mul[i] = mu;
  add[i] = beta[c] - mu * a * m;
}

__global__ void norm2(float* __restrict__ h, const float* __restrict__ mul, const float* __restrict__ add,
                      unsigned long long* __restrict__ keys){
  int tid  = blockIdx.x * 256 + threadIdx.x;
  int node = tid >> 5;
  int sl   = tid & 31;
  if (node >= TOTAL_N_) return;
  int b = node / NPG_;
  int nloc = node - b * NPG_;
  float v = h[(size_t)node * 32 + sl];
  v = lrelu(fmaf(mul[b * 32 + sl], v, add[b * 32 + sl]));
  h[(size_t)node * 32 + sl] = v;
  float m = v;
  for (int o = 1; o < 32; o <<= 1) m = fmaxf(m, __shfl_xor(m, o));
  if (sl == 0){
    unsigned u = __float_as_uint(m);
    u ^= (u >> 31) ? 0xFFFFFFFFu : 0x80000000u;
    keys[(size_t)b * NKEY_ + nloc] = ((unsigned long long)(~u) << 32) | (unsigned)nloc;
  }
}

__global__ void emit2(const float* __restrict__ h2, const int* __restrict__ topidx, float* __restrict__ out){
  int b = blockIdx.x >> 6, k = blockIdx.x & 63;
  int lane = threadIdx.x;         // 32
  int nloc = topidx[b * 64 + k];
  float v = h2[((size_t)b * NPG_ + nloc) * 32 + lane];
  for (int k2 = 2; k2 <= 32; k2 <<= 1){
    for (int j = k2 >> 1; j > 0; j >>= 1){
      float o = __shfl_xor(v, j);
      bool up    = ((lane & k2) == 0);
      bool lower = ((lane & j) == 0);
      v = (up == lower) ? fminf(v, o) : fmaxf(v, o);
    }
  }
  out[(size_t)b * OUT_ROW + 8192 + (size_t)k * 32 + lane] = lrelu(v);
}

__global__ void sentinel_kernel(float* out){
  int i = blockIdx.x * 256 + threadIdx.x;
  if (i < B_ * OUT_ROW) out[i] = -777.0f;
}

extern "C" void kernel_launch(void* const* d_in, const int* in_sizes, int n_in,
                              void* d_out, int out_size, void* d_ws, size_t ws_size,
                              hipStream_t stream){
  const float* feat   = (const float*)d_in[0];
  const float* ew     = (const float*)d_in[1];
  const float* W1     = (const float*)d_in[2];
  const float* W2     = (const float*)d_in[3];
  const float* gamma1 = (const float*)d_in[4];
  const float* beta1  = (const float*)d_in[5];
  const float* alpha1 = (const float*)d_in[6];
  const float* gamma2 = (const float*)d_in[7];
  const float* beta2  = (const float*)d_in[8];
  const float* alpha2 = (const float*)d_in[9];
  const int*   esrc   = (const int*)d_in[10];
  const int*   edst   = (const int*)d_in[11];
  float* out = (float*)d_out;

  char* ws = (char*)d_ws;
  auto alloc = [&](size_t bytes) -> char* {
    char* p = ws;
    ws += (bytes + 255) & ~(size_t)255;
    return p;
  };

  // zeroed region (must stay first & contiguous)
  int*   in_cnt  = (int*)  alloc((size_t)TOTAL_N_ * 4);
  int*   out_cnt = (int*)  alloc((size_t)TOTAL_N_ * 4);
  int*   cursor  = (int*)  alloc((size_t)TOTAL_N_ * 4);
  float* gsum1   = (float*)alloc(1024 * 4);
  float* gsq1    = (float*)alloc(1024 * 4);
  float* gsum2   = (float*)alloc(256 * 4);
  float* gsq2    = (float*)alloc(256 * 4);
  size_t zero_bytes = (size_t)(ws - (char*)d_ws);

  float* rsq_in  = (float*)alloc((size_t)TOTAL_N_ * 4);
  float* rsq_out = (float*)alloc((size_t)TOTAL_N_ * 4);
  int*   off     = (int*)  alloc((size_t)TOTAL_N_ * 4);
  int*   bsum    = (int*)  alloc(512 * 4);
  float* mul1    = (float*)alloc(1024 * 4);
  float* add1    = (float*)alloc(1024 * 4);
  float* mul2    = (float*)alloc(256 * 4);
  float* add2    = (float*)alloc(256 * 4);
  int*   topidx1 = (int*)  alloc(512 * 4);
  int*   topidx2 = (int*)  alloc(512 * 4);
  unsigned long long* cand = (unsigned long long*)alloc((size_t)B_ * 512 * 8);
  unsigned long long* keys = (unsigned long long*)alloc((size_t)B_ * NKEY_ * 8);
  int*   csr_src = (int*)  alloc((size_t)TOTAL_E_ * 4);
  float* csr_w   = (float*)alloc((size_t)TOTAL_E_ * 4);
  float* csr_wr  = (float*)alloc((size_t)TOTAL_E_ * 4);
  float* h2p     = (float*)alloc((size_t)TOTAL_N_ * 32 * 4);
  float* h2c     = (float*)alloc((size_t)TOTAL_N_ * 32 * 4);
  float* h1      = (float*)alloc((size_t)TOTAL_N_ * 128 * 4);

  size_t need = (size_t)(ws - (char*)d_ws);
  if (need > ws_size){
    sentinel_kernel<<<(B_ * OUT_ROW + 255) / 256, 256, 0, stream>>>(out);
    return;
  }

  hipMemsetAsync(d_ws, 0, zero_bytes, stream);
  hipMemsetAsync(keys, 0xFF, (size_t)B_ * NKEY_ * 8, stream);

  deg_kernel <<<(TOTAL_E_ + 255) / 256, 256, 0, stream>>>(esrc, edst, out_cnt, in_cnt);
  rsq_kernel <<<NB_SCAN, 256, 0, stream>>>(in_cnt, out_cnt, rsq_in, rsq_out);
  scan_blocks<<<NB_SCAN, 256, 0, stream>>>(in_cnt, off, bsum);
  scan_sums  <<<1, 512, 0, stream>>>(bsum, NB_SCAN);
  scan_add   <<<NB_SCAN, 256, 0, stream>>>(off, bsum);
  fill_csr   <<<(TOTAL_E_ + 255) / 256, 256, 0, stream>>>(esrc, edst, ew, rsq_out, off, cursor,
                                                          csr_src, csr_w, csr_wr);

  // layer 1
  spmm1_fused<<<NBLK_, 256, 0, stream>>>(off, in_cnt, csr_src, csr_wr, feat, W1, rsq_in, h1,
                                         gsum1, gsq1);
  finalize1  <<<1, 1024, 0, stream>>>(gsum1, gsq1, gamma1, beta1, alpha1, mul1, add1);
  normproj   <<<NBLK_, 256, 0, stream>>>(h1, mul1, add1, rsq_out, W2, keys, h2p);
  topk_s1    <<<B_ * 8, 256, 0, stream>>>(keys, cand);
  topk_s2    <<<B_, 256, 0, stream>>>(cand, topidx1);
  emit1      <<<B_ * 64, 128, 0, stream>>>(h1, topidx1, mul1, add1, out);

  // layer 2
  spmm2_fused<<<NBLK_, 256, 0, stream>>>(off, in_cnt, csr_src, csr_w, rsq_in, h2p, h2c,
                                         gsum2, gsq2);
  finalize2  <<<1, 256, 0, stream>>>(gsum2, gsq2, gamma2, beta2, alpha2, mul2, add2);
  norm2      <<<TOTAL_N_ * 32 / 256, 256, 0, stream>>>(h2c, mul2, add2, keys);
  topk_s1    <<<B_ * 8, 256, 0, stream>>>(keys, cand);
  topk_s2    <<<B_, 256, 0, stream>>>(cand, topidx2);
  emit2      <<<B_ * 64, 32, 0, stream>>>(h2c, topidx2, out);
}

// Round 8
// 724.853 us; speedup vs baseline: 2.3366x; 1.0640x over previous
//
#include <hip/hip_runtime.h>
#include <cstdint>

// ---- problem constants ----
constexpr int B_       = 8;
constexpr int NPG_     = 12500;    // nodes per graph
constexpr int KSEL_    = 64;       // sort-pool k
constexpr int TOTAL_N_ = 100000;
constexpr int TOTAL_E_ = 1600000;
constexpr int NKEY_    = 16384;    // padded per-graph key count (pow2 >= NPG_)
constexpr int NB_SCAN  = (TOTAL_N_ + 255) / 256;   // 391
constexpr int OUT_ROW  = KSEL_ * (128 + 32);       // 10240
constexpr int NBLK_    = 1024;     // 256-thread blocks, 4 blocks/CU
constexpr int WSTRIDE_ = 512;      // wave slots per graph

typedef float f2v __attribute__((ext_vector_type(2)));

__device__ __forceinline__ float lrelu(float v){ return v >= 0.f ? v : 0.01f * v; }
__device__ __forceinline__ int   rlanei(int x, int l){ return __builtin_amdgcn_readlane(x, l); }
__device__ __forceinline__ float rlanef(float x, int l){
  return __uint_as_float(__builtin_amdgcn_readlane((int)__float_as_uint(x), l));
}

// ---------------- degrees ----------------
__global__ void deg_kernel(const int* __restrict__ src, const int* __restrict__ dst,
                           int* __restrict__ out_cnt, int* __restrict__ in_cnt){
  int i = blockIdx.x * 256 + threadIdx.x;
  if (i < TOTAL_E_){
    atomicAdd(&out_cnt[src[i]], 1);
    atomicAdd(&in_cnt[dst[i]], 1);
  }
}

// ---------------- scan (block phase) + rsq in one pass ----------------
__global__ void scan_rsq(const int* __restrict__ in_cnt, const int* __restrict__ out_cnt,
                         int* __restrict__ off, int* __restrict__ bsum,
                         float* __restrict__ rsq_in, float* __restrict__ rsq_out){
  __shared__ int tmp[256];
  int t = threadIdx.x;
  int i = blockIdx.x * 256 + t;
  int x = (i < TOTAL_N_) ? in_cnt[i] : 0;
  tmp[t] = x;
  __syncthreads();
  for (int d = 1; d < 256; d <<= 1){
    int v = (t >= d) ? tmp[t - d] : 0;
    __syncthreads();
    tmp[t] += v;
    __syncthreads();
  }
  if (i < TOTAL_N_){
    off[i] = tmp[t] - x;                 // block-local exclusive
    int ic = x  < 1 ? 1 : x;
    int oc = out_cnt[i]; if (oc < 1) oc = 1;
    rsq_in[i]  = rsqrtf((float)ic);
    rsq_out[i] = rsqrtf((float)oc);
  }
  if (t == 255) bsum[blockIdx.x] = tmp[255];
}

__global__ void scan_sums(int* __restrict__ bsum, int nb){
  __shared__ int tmp[512];
  int t = threadIdx.x;
  int x = (t < nb) ? bsum[t] : 0;
  tmp[t] = x;
  __syncthreads();
  for (int d = 1; d < 512; d <<= 1){
    int v = (t >= d) ? tmp[t - d] : 0;
    __syncthreads();
    tmp[t] += v;
    __syncthreads();
  }
  if (t < nb) bsum[t] = tmp[t] - x;      // exclusive block offsets
}

// ---------------- featS = feat * rsq_out[row] ----------------
__global__ void featscale(const float* __restrict__ feat, const float* __restrict__ rsq_out,
                          float* __restrict__ featS){
  int i = blockIdx.x * 256 + threadIdx.x;      // f2v index
  if (i < TOTAL_N_ * 32){
    f2v v = ((const f2v*)feat)[i];
    float r = rsq_out[i >> 5];
    v.x *= r; v.y *= r;
    ((f2v*)featS)[i] = v;
  }
}

// ---------------- CSR fill: single int2 (src, ew) scatter ----------------
__global__ void fill_csr(const int* __restrict__ src, const int* __restrict__ dst,
                         const float* __restrict__ ew,
                         const int* __restrict__ off, const int* __restrict__ bsum,
                         int* __restrict__ cursor, int2* __restrict__ csr){
  int i = blockIdx.x * 256 + threadIdx.x;
  if (i < TOTAL_E_){
    int d = dst[i];
    int p = atomicAdd(&cursor[d], 1);
    int slot = off[d] + bsum[d >> 8] + p;
    csr[slot] = make_int2(src[i], __float_as_int(ew[i]));
  }
}

// ---------------- layer 1: fused SpMM (64-d) + W1 projection + stats ----------------
// h1_raw[v][c] = rsq_in[v] * sum_k ( sum_e ew * featS[src][k] ) * W1[k][c]
__global__ __launch_bounds__(256, 4)
void spmm1_fused(const int* __restrict__ off, const int* __restrict__ bsum,
                 const int* __restrict__ cnt, const int2* __restrict__ csr,
                 const float* __restrict__ featS, const float* __restrict__ W1,
                 const float* __restrict__ rsq_in, float* __restrict__ h1,
                 float* __restrict__ gsum, float* __restrict__ gsq){
  __shared__ float wsh[64 * 128];   // 32 KB
  __shared__ float sred[4][256];    // 4 KB
  int t = threadIdx.x;
  for (int i = t; i < 64 * 128; i += 256) wsh[i] = W1[i];
  __syncthreads();

  int g     = blockIdx.x & 7;                       // graph == XCD round-robin
  int wslot = (blockIdx.x >> 3) * 4 + (t >> 6);     // 0..511
  int lane  = t & 63;

  // lane i (<32) holds global off/cnt of node (wslot + i*WSTRIDE_)
  int pof = 0, pcn = 0;
  {
    int nl = wslot + lane * WSTRIDE_;
    if (lane < 32 && nl < NPG_){
      int v = g * NPG_ + nl;
      pof = off[v] + bsum[v >> 8];
      pcn = cnt[v];
    }
  }
  int nv = (NPG_ - wslot + WSTRIDE_ - 1) / WSTRIDE_;   // 24 or 25

  float s0 = 0.f, q0 = 0.f, s1 = 0.f, q1 = 0.f;

  // csr batch prefetch pipeline
  int ms = 0, msn = 0; float mw = 0.f, mwn = 0.f;
  {
    int sb = rlanei(pof, 0);
    int n  = rlanei(pcn, 0);
    int b  = n < 64 ? n : 64;
    if (lane < b){ int2 e = csr[sb + lane]; ms = e.x; mw = __int_as_float(e.y); }
  }

  for (int i = 0; i < nv; ++i){
    int sbase = rlanei(pof, i);
    int n     = rlanei(pcn, i);
    int batch = n < 64 ? n : 64;
    if (i + 1 < nv){
      int sb = rlanei(pof, i + 1);
      int n1 = rlanei(pcn, i + 1);
      int b1 = n1 < 64 ? n1 : 64;
      msn = 0; mwn = 0.f;
      if (lane < b1){ int2 e = csr[sb + lane]; msn = e.x; mwn = __int_as_float(e.y); }
    }

    float acc = 0.f;
    int j = 0;
    #pragma unroll 1
    for (; j + 8 <= batch; j += 8){
      int   a0 = rlanei(ms, j+0), a1 = rlanei(ms, j+1), a2 = rlanei(ms, j+2), a3 = rlanei(ms, j+3);
      int   a4 = rlanei(ms, j+4), a5 = rlanei(ms, j+5), a6 = rlanei(ms, j+6), a7 = rlanei(ms, j+7);
      float w0 = rlanef(mw, j+0), w1 = rlanef(mw, j+1), w2 = rlanef(mw, j+2), w3 = rlanef(mw, j+3);
      float w4 = rlanef(mw, j+4), w5 = rlanef(mw, j+5), w6 = rlanef(mw, j+6), w7 = rlanef(mw, j+7);
      float f0 = featS[(size_t)a0 * 64 + lane];
      float f1 = featS[(size_t)a1 * 64 + lane];
      float f2 = featS[(size_t)a2 * 64 + lane];
      float f3 = featS[(size_t)a3 * 64 + lane];
      float f4 = featS[(size_t)a4 * 64 + lane];
      float f5 = featS[(size_t)a5 * 64 + lane];
      float f6 = featS[(size_t)a6 * 64 + lane];
      float f7 = featS[(size_t)a7 * 64 + lane];
      acc = fmaf(w0, f0, acc); acc = fmaf(w1, f1, acc);
      acc = fmaf(w2, f2, acc); acc = fmaf(w3, f3, acc);
      acc = fmaf(w4, f4, acc); acc = fmaf(w5, f5, acc);
      acc = fmaf(w6, f6, acc); acc = fmaf(w7, f7, acc);
    }
    #pragma unroll 1
    for (; j < batch; ++j){
      acc = fmaf(rlanef(mw, j), featS[(size_t)rlanei(ms, j) * 64 + lane], acc);
    }
    if (n > 64){   // statistically never; correctness fallback
      for (int e = 64; e < n; ++e){
        int2 ed = csr[sbase + e];
        acc = fmaf(__int_as_float(ed.y), featS[(size_t)ed.x * 64 + lane], acc);
      }
    }

    // epilogue: project 64 -> 128; lane owns output cols 2*lane, 2*lane+1
    f2v A = {0.f, 0.f};
    const f2v* wp = (const f2v*)wsh;
    #pragma unroll
    for (int k = 0; k < 64; ++k){
      float ak = rlanef(acc, k);
      f2v wv = wp[k * 64 + lane];
      A.x = fmaf(ak, wv.x, A.x);
      A.y = fmaf(ak, wv.y, A.y);
    }
    int v = g * NPG_ + wslot + i * WSTRIDE_;
    float ri = rsq_in[v];
    A.x *= ri; A.y *= ri;
    __builtin_nontemporal_store(A, (f2v*)&h1[(size_t)v * 128 + 2 * lane]);  // keep L2 for featS
    s0 += A.x; q0 = fmaf(A.x, A.x, q0);
    s1 += A.y; q1 = fmaf(A.y, A.y, q1);

    ms = msn; mw = mwn;
  }

  // block-level stats reduce, then atomics
  __syncthreads();
  sred[0][t] = s0; sred[1][t] = q0; sred[2][t] = s1; sred[3][t] = q1;
  __syncthreads();
  if (t < 64){
    float S0 = sred[0][t] + sred[0][t+64] + sred[0][t+128] + sred[0][t+192];
    float Q0 = sred[1][t] + sred[1][t+64] + sred[1][t+128] + sred[1][t+192];
    float S1 = sred[2][t] + sred[2][t+64] + sred[2][t+128] + sred[2][t+192];
    float Q1 = sred[3][t] + sred[3][t+64] + sred[3][t+128] + sred[3][t+192];
    atomicAdd(&gsum[g * 128 + 2*t],     S0);
    atomicAdd(&gsq [g * 128 + 2*t],     Q0);
    atomicAdd(&gsum[g * 128 + 2*t + 1], S1);
    atomicAdd(&gsq [g * 128 + 2*t + 1], Q1);
  }
}

__global__ void finalize1(const float* __restrict__ gsum, const float* __restrict__ gsq,
                          const float* __restrict__ gamma, const float* __restrict__ beta,
                          const float* __restrict__ alpha, float* __restrict__ mul, float* __restrict__ add){
  int i = threadIdx.x;            // 1024 = 8*128
  int c = i & 127;
  const float invn = 1.0f / (float)NPG_;
  float m = gsum[i] * invn;
  float a = alpha[c];
  float var = gsq[i] * invn - 2.f * a * m * m + a * a * m * m;
  float mu = gamma[c] * rsqrtf(var + 1e-5f);
  mul[i] = mu;
  add[i] = beta[c] - mu * a * m;
}

// ---------------- fused: normalize h1 (in regs) + sort keys + project to h2p ----------------
__global__ __launch_bounds__(256, 4)
void normproj(const float* __restrict__ h1,
              const float* __restrict__ mul, const float* __restrict__ add,
              const float* __restrict__ rsq_out, const float* __restrict__ W2,
              unsigned long long* __restrict__ keys, float* __restrict__ h2p){
  __shared__ float w2s[128 * 32];  // 16 KB
  int t = threadIdx.x;
  for (int i = t; i < 128 * 32; i += 256) w2s[i] = W2[i];
  __syncthreads();

  int g     = blockIdx.x & 7;
  int wslot = (blockIdx.x >> 3) * 4 + (t >> 6);
  int lane  = t & 63;
  int c     = lane & 31, hh = lane >> 5;
  int wbase = hh * 64 * 32 + c;

  float m0 = mul[g * 128 + lane],      aa0 = add[g * 128 + lane];
  float m1 = mul[g * 128 + 64 + lane], aa1 = add[g * 128 + 64 + lane];

  int nv = (NPG_ - wslot + WSTRIDE_ - 1) / WSTRIDE_;

  int v0 = g * NPG_ + wslot;
  float x0 = __builtin_nontemporal_load(&h1[(size_t)v0 * 128 + lane]);
  float x1 = __builtin_nontemporal_load(&h1[(size_t)v0 * 128 + 64 + lane]);

  for (int i = 0; i < nv; ++i){
    int v = g * NPG_ + wslot + i * WSTRIDE_;
    float cur0 = x0, cur1 = x1;
    if (i + 1 < nv){
      int vn = v + WSTRIDE_;
      x0 = __builtin_nontemporal_load(&h1[(size_t)vn * 128 + lane]);
      x1 = __builtin_nontemporal_load(&h1[(size_t)vn * 128 + 64 + lane]);
    }
    float y0 = lrelu(fmaf(m0, cur0, aa0));
    float y1 = lrelu(fmaf(m1, cur1, aa1));
    float mx = fmaxf(y0, y1);
    for (int o = 1; o < 64; o <<= 1) mx = fmaxf(mx, __shfl_xor(mx, o));
    if (lane == 0){
      unsigned u = __float_as_uint(mx);
      u ^= (u >> 31) ? 0xFFFFFFFFu : 0x80000000u;
      int nloc = v - g * NPG_;
      keys[(size_t)g * NKEY_ + nloc] = ((unsigned long long)(~u) << 32) | (unsigned)nloc;
    }
    float acc = 0.f;
    #pragma unroll
    for (int kk = 0; kk < 64; ++kk){
      float sa = rlanef(y0, kk);
      float sb = rlanef(y1, kk);
      float vk = hh ? sb : sa;
      acc = fmaf(vk, w2s[wbase + kk * 32], acc);
    }
    acc += __shfl_xor(acc, 32);
    if (hh == 0) h2p[(size_t)v * 32 + c] = acc * rsq_out[v];   // cached: spmm2 gathers this
  }
}

// ---------------- top-k selection (2-stage bitonic) ----------------
__global__ void topk_s1(const unsigned long long* __restrict__ keys, unsigned long long* __restrict__ cand){
  __shared__ unsigned long long s[2048];
  int b = blockIdx.x >> 3, ch = blockIdx.x & 7;
  int t = threadIdx.x;            // 256
  for (int i = t; i < 2048; i += 256) s[i] = keys[(size_t)b * NKEY_ + (size_t)ch * 2048 + i];
  for (int k2 = 2; k2 <= 2048; k2 <<= 1){
    for (int j = k2 >> 1; j > 0; j >>= 1){
      __syncthreads();
      for (int i = t; i < 2048; i += 256){
        int p = i ^ j;
        if (p > i){
          unsigned long long A = s[i], C = s[p];
          bool up = ((i & k2) == 0);
          if ((A > C) == up){ s[i] = C; s[p] = A; }
        }
      }
    }
  }
  __syncthreads();
  if (t < 64) cand[(size_t)b * 512 + (size_t)ch * 64 + t] = s[t];
}

__global__ void topk_s2(const unsigned long long* __restrict__ cand, int* __restrict__ topidx){
  __shared__ unsigned long long s[512];
  int b = blockIdx.x;
  int t = threadIdx.x;            // 256
  for (int i = t; i < 512; i += 256) s[i] = cand[(size_t)b * 512 + i];
  for (int k2 = 2; k2 <= 512; k2 <<= 1){
    for (int j = k2 >> 1; j > 0; j >>= 1){
      __syncthreads();
      for (int i = t; i < 512; i += 256){
        int p = i ^ j;
        if (p > i){
          unsigned long long A = s[i], C = s[p];
          bool up = ((i & k2) == 0);
          if ((A > C) == up){ s[i] = C; s[p] = A; }
        }
      }
    }
  }
  __syncthreads();
  if (t < 64) topidx[b * 64 + t] = (int)(s[t] & 0xFFFFFFFFull);
}

// normalize selected raw h1 rows on the fly, sort 128 ascending, final leaky, write
__global__ void emit1(const float* __restrict__ h1, const int* __restrict__ topidx,
                      const float* __restrict__ mul, const float* __restrict__ add,
                      float* __restrict__ out){
  __shared__ float s[128];
  int b = blockIdx.x >> 6, k = blockIdx.x & 63;
  int t = threadIdx.x;            // 128
  int nloc = topidx[b * 64 + k];
  float raw = h1[((size_t)b * NPG_ + nloc) * 128 + t];
  s[t] = lrelu(fmaf(mul[b * 128 + t], raw, add[b * 128 + t]));
  for (int k2 = 2; k2 <= 128; k2 <<= 1){
    for (int j = k2 >> 1; j > 0; j >>= 1){
      __syncthreads();
      int p = t ^ j;
      if (p > t){
        float A = s[t], C = s[p];
        bool up = ((t & k2) == 0);
        if ((A > C) == up){ s[t] = C; s[p] = A; }
      }
    }
  }
  __syncthreads();
  out[(size_t)b * OUT_ROW + (size_t)k * 128 + t] = lrelu(s[t]);
}

// ---------------- layer 2: SpMM on projected h2p (32-d rows) + stats ----------------
__global__ __launch_bounds__(256, 4)
void spmm2_fused(const int* __restrict__ off, const int* __restrict__ bsum,
                 const int* __restrict__ cnt, const int2* __restrict__ csr,
                 const float* __restrict__ rsq_in, const float* __restrict__ h2p,
                 float* __restrict__ h2c,
                 float* __restrict__ gsum, float* __restrict__ gsq){
  __shared__ float sred[2][256];
  int t     = threadIdx.x;
  int g     = blockIdx.x & 7;
  int wslot = (blockIdx.x >> 3) * 4 + (t >> 6);
  int lane  = t & 63;
  int c     = lane & 31, hh = lane >> 5;

  int pof = 0, pcn = 0;
  {
    int nl = wslot + lane * WSTRIDE_;
    if (lane < 32 && nl < NPG_){
      int v = g * NPG_ + nl;
      pof = off[v] + bsum[v >> 8];
      pcn = cnt[v];
    }
  }
  int nv = (NPG_ - wslot + WSTRIDE_ - 1) / WSTRIDE_;

  float ssum = 0.f, ssq = 0.f;

  int ms = 0, msn = 0; float mw = 0.f, mwn = 0.f;
  {
    int sb = rlanei(pof, 0);
    int n  = rlanei(pcn, 0);
    int b  = n < 64 ? n : 64;
    if (lane < b){ int2 e = csr[sb + lane]; ms = e.x; mw = __int_as_float(e.y); }
  }

  for (int i = 0; i < nv; ++i){
    int sbase = rlanei(pof, i);
    int n     = rlanei(pcn, i);
    int batch = n < 64 ? n : 64;
    if (i + 1 < nv){
      int sb = rlanei(pof, i + 1);
      int n1 = rlanei(pcn, i + 1);
      int b1 = n1 < 64 ? n1 : 64;
      msn = 0; mwn = 0.f;
      if (lane < b1){ int2 e = csr[sb + lane]; msn = e.x; mwn = __int_as_float(e.y); }
    }

    // paired halves: lower half even edges, upper half odd; 8 loads in flight over 16 edges
    float acc = 0.f;
    int j = 0;
    int bulk = batch & ~15;
    #pragma unroll 1
    for (; j < bulk; j += 16){
      int   sL0 = rlanei(ms, j+ 0), sH0 = rlanei(ms, j+ 1);
      int   sL1 = rlanei(ms, j+ 2), sH1 = rlanei(ms, j+ 3);
      int   sL2 = rlanei(ms, j+ 4), sH2 = rlanei(ms, j+ 5);
      int   sL3 = rlanei(ms, j+ 6), sH3 = rlanei(ms, j+ 7);
      int   sL4 = rlanei(ms, j+ 8), sH4 = rlanei(ms, j+ 9);
      int   sL5 = rlanei(ms, j+10), sH5 = rlanei(ms, j+11);
      int   sL6 = rlanei(ms, j+12), sH6 = rlanei(ms, j+13);
      int   sL7 = rlanei(ms, j+14), sH7 = rlanei(ms, j+15);
      float wL0 = rlanef(mw, j+ 0), wH0 = rlanef(mw, j+ 1);
      float wL1 = rlanef(mw, j+ 2), wH1 = rlanef(mw, j+ 3);
      float wL2 = rlanef(mw, j+ 4), wH2 = rlanef(mw, j+ 5);
      float wL3 = rlanef(mw, j+ 6), wH3 = rlanef(mw, j+ 7);
      float wL4 = rlanef(mw, j+ 8), wH4 = rlanef(mw, j+ 9);
      float wL5 = rlanef(mw, j+10), wH5 = rlanef(mw, j+11);
      float wL6 = rlanef(mw, j+12), wH6 = rlanef(mw, j+13);
      float wL7 = rlanef(mw, j+14), wH7 = rlanef(mw, j+15);
      int   e0 = hh ? sH0 : sL0;  float g0 = hh ? wH0 : wL0;
      int   e1 = hh ? sH1 : sL1;  float g1 = hh ? wH1 : wL1;
      int   e2 = hh ? sH2 : sL2;  float g2 = hh ? wH2 : wL2;
      int   e3 = hh ? sH3 : sL3;  float g3 = hh ? wH3 : wL3;
      int   e4 = hh ? sH4 : sL4;  float g4 = hh ? wH4 : wL4;
      int   e5 = hh ? sH5 : sL5;  float g5 = hh ? wH5 : wL5;
      int   e6 = hh ? sH6 : sL6;  float g6 = hh ? wH6 : wL6;
      int   e7 = hh ? sH7 : sL7;  float g7 = hh ? wH7 : wL7;
      float f0 = h2p[(size_t)e0 * 32 + c];
      float f1 = h2p[(size_t)e1 * 32 + c];
      float f2 = h2p[(size_t)e2 * 32 + c];
      float f3 = h2p[(size_t)e3 * 32 + c];
      float f4 = h2p[(size_t)e4 * 32 + c];
      float f5 = h2p[(size_t)e5 * 32 + c];
      float f6 = h2p[(size_t)e6 * 32 + c];
      float f7 = h2p[(size_t)e7 * 32 + c];
      acc = fmaf(g0, f0, acc); acc = fmaf(g1, f1, acc);
      acc = fmaf(g2, f2, acc); acc = fmaf(g3, f3, acc);
      acc = fmaf(g4, f4, acc); acc = fmaf(g5, f5, acc);
      acc = fmaf(g6, f6, acc); acc = fmaf(g7, f7, acc);
    }
    #pragma unroll 1
    for (; j < batch; j += 2){
      int jb = j + 1; if (jb > 63) jb = 63;   // lane jb holds w=0 if >= batch
      int   sA = rlanei(ms, j);  float wA = rlanef(mw, j);
      int   sB = rlanei(ms, jb); float wB = rlanef(mw, jb);
      int   s  = hh ? sB : sA;
      float wg = hh ? wB : wA;
      acc = fmaf(wg, h2p[(size_t)s * 32 + c], acc);
    }
    acc += __shfl_xor(acc, 32);
    if (n > 64){
      for (int e = 64; e < n; ++e){
        int2 ed = csr[sbase + e];
        acc = fmaf(__int_as_float(ed.y), h2p[(size_t)ed.x * 32 + c], acc);
      }
    }
    int v = g * NPG_ + wslot + i * WSTRIDE_;
    float val = acc * rsq_in[v];
    if (hh == 0){
      __builtin_nontemporal_store(val, &h2c[(size_t)v * 32 + c]);  // keep L2 for h2p
      ssum += val; ssq = fmaf(val, val, ssq);
    }
    ms = msn; mw = mwn;
  }

  __syncthreads();
  sred[0][t] = ssum; sred[1][t] = ssq;
  __syncthreads();
  if (t < 32){
    float S = 0.f, Q = 0.f;
    #pragma unroll
    for (int w = 0; w < 4; ++w){
      S += sred[0][t + 64*w] + sred[0][t + 32 + 64*w];
      Q += sred[1][t + 64*w] + sred[1][t + 32 + 64*w];
    }
    atomicAdd(&gsum[g * 32 + t], S);
    atomicAdd(&gsq [g * 32 + t], Q);
  }
}

__global__ void finalize2(const float* __restrict__ gsum, const float* __restrict__ gsq,
                          const float* __restrict__ gamma, const float* __restrict__ beta,
                          const float* __restrict__ alpha, float* __restrict__ mul, float* __restrict__ add){
  int i = threadIdx.x;            // 256 = 8*32
  int c = i & 31;
  const float invn = 1.0f / (float)NPG_;
  float m = gsum[i] * invn;
  float a = alpha[c];
  float var = gsq[i] * invn - 2.f * a * m * m + a * a * m * m;
  float mu = gamma[c] * rsqrtf(var + 1e-5f);
  mul[i] = mu;
  add[i] = beta[c] - mu * a * m;
}

__global__ void norm2(float* __restrict__ h, const float* __restrict__ mul, const float* __restrict__ add,
                      unsigned long long* __restrict__ keys){
  int tid  = blockIdx.x * 256 + threadIdx.x;
  int node = tid >> 5;
  int sl   = tid & 31;
  if (node >= TOTAL_N_) return;
  int b = node / NPG_;
  int nloc = node - b * NPG_;
  float v = h[(size_t)node * 32 + sl];
  v = lrelu(fmaf(mul[b * 32 + sl], v, add[b * 32 + sl]));
  h[(size_t)node * 32 + sl] = v;
  float m = v;
  for (int o = 1; o < 32; o <<= 1) m = fmaxf(m, __shfl_xor(m, o));
  if (sl == 0){
    unsigned u = __float_as_uint(m);
    u ^= (u >> 31) ? 0xFFFFFFFFu : 0x80000000u;
    keys[(size_t)b * NKEY_ + nloc] = ((unsigned long long)(~u) << 32) | (unsigned)nloc;
  }
}

__global__ void emit2(const float* __restrict__ h2, const int* __restrict__ topidx, float* __restrict__ out){
  int b = blockIdx.x >> 6, k = blockIdx.x & 63;
  int lane = threadIdx.x;         // 32
  int nloc = topidx[b * 64 + k];
  float v = h2[((size_t)b * NPG_ + nloc) * 32 + lane];
  for (int k2 = 2; k2 <= 32; k2 <<= 1){
    for (int j = k2 >> 1; j > 0; j >>= 1){
      float o = __shfl_xor(v, j);
      bool up    = ((lane & k2) == 0);
      bool lower = ((lane & j) == 0);
      v = (up == lower) ? fminf(v, o) : fmaxf(v, o);
    }
  }
  out[(size_t)b * OUT_ROW + 8192 + (size_t)k * 32 + lane] = lrelu(v);
}

__global__ void sentinel_kernel(float* out){
  int i = blockIdx.x * 256 + threadIdx.x;
  if (i < B_ * OUT_ROW) out[i] = -777.0f;
}

extern "C" void kernel_launch(void* const* d_in, const int* in_sizes, int n_in,
                              void* d_out, int out_size, void* d_ws, size_t ws_size,
                              hipStream_t stream){
  const float* feat   = (const float*)d_in[0];
  const float* ew     = (const float*)d_in[1];
  const float* W1     = (const float*)d_in[2];
  const float* W2     = (const float*)d_in[3];
  const float* gamma1 = (const float*)d_in[4];
  const float* beta1  = (const float*)d_in[5];
  const float* alpha1 = (const float*)d_in[6];
  const float* gamma2 = (const float*)d_in[7];
  const float* beta2  = (const float*)d_in[8];
  const float* alpha2 = (const float*)d_in[9];
  const int*   esrc   = (const int*)d_in[10];
  const int*   edst   = (const int*)d_in[11];
  float* out = (float*)d_out;

  char* ws = (char*)d_ws;
  auto alloc = [&](size_t bytes) -> char* {
    char* p = ws;
    ws += (bytes + 255) & ~(size_t)255;
    return p;
  };

  // zeroed region (must stay first & contiguous)
  int*   in_cnt  = (int*)  alloc((size_t)TOTAL_N_ * 4);
  int*   out_cnt = (int*)  alloc((size_t)TOTAL_N_ * 4);
  int*   cursor  = (int*)  alloc((size_t)TOTAL_N_ * 4);
  float* gsum1   = (float*)alloc(1024 * 4);
  float* gsq1    = (float*)alloc(1024 * 4);
  float* gsum2   = (float*)alloc(256 * 4);
  float* gsq2    = (float*)alloc(256 * 4);
  size_t zero_bytes = (size_t)(ws - (char*)d_ws);

  float* rsq_in  = (float*)alloc((size_t)TOTAL_N_ * 4);
  float* rsq_out = (float*)alloc((size_t)TOTAL_N_ * 4);
  int*   off     = (int*)  alloc((size_t)TOTAL_N_ * 4);
  int*   bsum    = (int*)  alloc(512 * 4);
  float* mul1    = (float*)alloc(1024 * 4);
  float* add1    = (float*)alloc(1024 * 4);
  float* mul2    = (float*)alloc(256 * 4);
  float* add2    = (float*)alloc(256 * 4);
  int*   topidx1 = (int*)  alloc(512 * 4);
  int*   topidx2 = (int*)  alloc(512 * 4);
  unsigned long long* cand = (unsigned long long*)alloc((size_t)B_ * 512 * 8);
  unsigned long long* keys = (unsigned long long*)alloc((size_t)B_ * NKEY_ * 8);
  int2*  csr     = (int2*) alloc((size_t)TOTAL_E_ * 8);
  // featS (25.6MB) aliases the h2p+h2c region (dead until normproj/spmm2)
  float* h2p     = (float*)alloc((size_t)TOTAL_N_ * 32 * 4);
  float* h2c     = (float*)alloc((size_t)TOTAL_N_ * 32 * 4);
  float* featS   = h2p;
  float* h1      = (float*)alloc((size_t)TOTAL_N_ * 128 * 4);

  size_t need = (size_t)(ws - (char*)d_ws);
  if (need > ws_size){
    sentinel_kernel<<<(B_ * OUT_ROW + 255) / 256, 256, 0, stream>>>(out);
    return;
  }

  hipMemsetAsync(d_ws, 0, zero_bytes, stream);
  hipMemsetAsync(keys, 0xFF, (size_t)B_ * NKEY_ * 8, stream);

  const int EB = (TOTAL_E_ + 255) / 256;
  deg_kernel <<<EB, 256, 0, stream>>>(esrc, edst, out_cnt, in_cnt);
  scan_rsq   <<<NB_SCAN, 256, 0, stream>>>(in_cnt, out_cnt, off, bsum, rsq_in, rsq_out);
  scan_sums  <<<1, 512, 0, stream>>>(bsum, NB_SCAN);
  featscale  <<<(TOTAL_N_ * 32 + 255) / 256, 256, 0, stream>>>(feat, rsq_out, featS);
  fill_csr   <<<EB, 256, 0, stream>>>(esrc, edst, ew, off, bsum, cursor, csr);

  // layer 1
  spmm1_fused<<<NBLK_, 256, 0, stream>>>(off, bsum, in_cnt, csr, featS, W1, rsq_in, h1,
                                         gsum1, gsq1);
  finalize1  <<<1, 1024, 0, stream>>>(gsum1, gsq1, gamma1, beta1, alpha1, mul1, add1);
  normproj   <<<NBLK_, 256, 0, stream>>>(h1, mul1, add1, rsq_out, W2, keys, h2p);
  topk_s1    <<<B_ * 8, 256, 0, stream>>>(keys, cand);
  topk_s2    <<<B_, 256, 0, stream>>>(cand, topidx1);
  emit1      <<<B_ * 64, 128, 0, stream>>>(h1, topidx1, mul1, add1, out);

  // layer 2
  spmm2_fused<<<NBLK_, 256, 0, stream>>>(off, bsum, in_cnt, csr, rsq_in, h2p, h2c,
                                         gsum2, gsq2);
  finalize2  <<<1, 256, 0, stream>>>(gsum2, gsq2, gamma2, beta2, alpha2, mul2, add2);
  norm2      <<<TOTAL_N_ * 32 / 256, 256, 0, stream>>>(h2c, mul2, add2, keys);
  topk_s1    <<<B_ * 8, 256, 0, stream>>>(keys, cand);
  topk_s2    <<<B_, 256, 0, stream>>>(cand, topidx2);
  emit2      <<<B_ * 64, 32, 0, stream>>>(h2c, topidx2, out);
}